// Round 14
// baseline (118.825 us; speedup 1.0000x reference)
//
#include <hip/hip_runtime.h>
#include <hip/hip_bf16.h>

// ===== R14: MEASUREMENT ROUND =====
// Identical to R11 except k_rec is launched TWICE (both write d_out with
// identical values; deterministic). T14 - T11 = k_rec duration exactly,
// resolving the k_rec-vs-prologue split that 6 null rounds left ambiguous.

// Problem sizes (fixed by the reference)
#define S_LEN 256     // sequence length (t)
#define DM    512     // d_model (k / d)
#define DR    512     // d_rnn (s)

typedef float f4 __attribute__((ext_vector_type(4)));
typedef float f2 __attribute__((ext_vector_type(2)));

// ws layout (floats):
//   xT  : [512][256]     at 0       (131072)
//   acT : f2[512][256]   at 131072  (262144)

__global__ __launch_bounds__(256) void k_transpose_x(const float* __restrict__ x,
                                                     float* __restrict__ xT) {
    __shared__ float tile[32][33];
    const int k0 = blockIdx.x * 32;
    const int t0 = blockIdx.y * 32;
    const int lx = threadIdx.x & 31;
    const int ly = threadIdx.x >> 5;
#pragma unroll
    for (int i = 0; i < 32; i += 8)
        tile[ly + i][lx] = x[(t0 + ly + i) * DM + k0 + lx];
    __syncthreads();
#pragma unroll
    for (int i = 0; i < 32; i += 8)
        xT[(k0 + ly + i) * S_LEN + t0 + lx] = tile[lx][ly + i];
}

// grid(256): block g computes GEMM rows {2g, 2g+1, 512+2g, 512+2g+1} over all t,
// then applies the sigmoid/softplus/exp epilogue and writes acT[s][t] = {a, c}.
__global__ __launch_bounds__(256) void k_gemm_act(const float* __restrict__ xT,
                                                  const float* __restrict__ W1,
                                                  const float* __restrict__ b1,
                                                  const float* __restrict__ Lam,
                                                  f2* __restrict__ acT) {
    const int g  = blockIdx.x;       // 0..255
    const int t  = threadIdx.x;      // lane axis = t (coalesced xT loads)
    const int r0 = 2 * g;

    float acc0 = 0.f, acc1 = 0.f, acc2 = 0.f, acc3 = 0.f;
    const float* __restrict__ xb = xT + t;
    const float* __restrict__ w0 = W1 + (r0)       * DM;   // wave-uniform → s_loads
    const float* __restrict__ w1 = W1 + (r0 + 1)   * DM;
    const float* __restrict__ w2 = W1 + (512 + r0) * DM;
    const float* __restrict__ w3 = W1 + (513 + r0) * DM;

#pragma unroll 8
    for (int k = 0; k < DM; ++k) {
        const float xv = xb[k * S_LEN];
        acc0 = fmaf(xv, w0[k], acc0);
        acc1 = fmaf(xv, w1[k], acc1);
        acc2 = fmaf(xv, w2[k], acc2);
        acc3 = fmaf(xv, w3[k], acc3);
    }

#pragma unroll
    for (int j = 0; j < 2; ++j) {
        const float pre_i = (j ? acc1 : acc0) + b1[r0 + j];
        const float pre_r = (j ? acc3 : acc2) + b1[512 + r0 + j];
        const float inp = 1.f / (1.f + expf(-pre_i));
        const float rec = 1.f / (1.f + expf(-pre_r));
        const float sp  = log1pf(expf(Lam[r0 + j]));
        const float a   = expf(-8.f * sp * rec);
        const float c   = sqrtf(fmaxf(1.f - a * a, 0.f)) * inp;
        f2 ac; ac.x = a; ac.y = c;
        acT[(r0 + j) * S_LEN + t] = ac;
    }
}

// grid(256) x 256: R11's k_rec, unchanged.
__global__ __launch_bounds__(256) void k_rec(const float* __restrict__ x,
                                             const float* __restrict__ state0,
                                             const f2* __restrict__ acT,
                                             f4* __restrict__ out4) {
    const int bx   = blockIdx.x;
    const int sp   = (bx & 7) * 32 + (bx >> 3);   // bijective XCD s-banding
    const int tid  = threadIdx.x;
    const int half = tid >> 7;           // 0 or 1
    const int s    = sp * 2 + half;
    const int dq   = tid & 127;          // d/4

    __shared__ f2 ac_l[2][S_LEN];        // {a, c} per (half, t)
    f2* lf = &ac_l[0][0];
    lf[tid]       = acT[sp * 2 * S_LEN + tid];
    lf[tid + 256] = acT[sp * 2 * S_LEN + tid + 256];
    __syncthreads();

    const f4* __restrict__ st4 = reinterpret_cast<const f4*>(state0);
    f4 h = st4[s * 128 + dq];

    const f4* __restrict__ x4 = reinterpret_cast<const f4*>(x);
    f4 xv = x4[dq];                      // t = 0 prefetch

#pragma unroll 4
    for (int t = 0; t < S_LEN; ++t) {
        f4 xn;
        if (t + 1 < S_LEN) xn = x4[(t + 1) * 128 + dq];
        else xn = (f4)0.f;

        const f2 ac = ac_l[half][t];               // LDS broadcast (wave-uniform)
        const float at = ac.x, ct = ac.y;
        h.x = fmaf(at, h.x, ct * xv.x);
        h.y = fmaf(at, h.y, ct * xv.y);
        h.z = fmaf(at, h.z, ct * xv.z);
        h.w = fmaf(at, h.w, ct * xv.w);

        __builtin_nontemporal_store(h, &out4[(t * DR + s) * 128 + dq]);
        xv = xn;
    }
    // final state
    out4[(S_LEN * DR) * 128 + s * 128 + dq] = h;
}

extern "C" void kernel_launch(void* const* d_in, const int* in_sizes, int n_in,
                              void* d_out, int out_size, void* d_ws, size_t ws_size,
                              hipStream_t stream) {
    const float* x      = (const float*)d_in[0];
    const float* state0 = (const float*)d_in[1];
    const float* W1     = (const float*)d_in[2];
    const float* b1     = (const float*)d_in[3];
    const float* Lam    = (const float*)d_in[4];

    float* ws  = (float*)d_ws;
    float* xT  = ws;                      // 131072 floats
    f2*    acT = (f2*)(ws + 131072);      // 131072 f2

    f4* out4 = (f4*)d_out;

    k_transpose_x<<<dim3(16, 8), 256, 0, stream>>>(x, xT);
    k_gemm_act<<<dim3(256), 256, 0, stream>>>(xT, W1, b1, Lam, acT);
    k_rec<<<dim3(256), 256, 0, stream>>>(x, state0, acT, out4);
    k_rec<<<dim3(256), 256, 0, stream>>>(x, state0, acT, out4);  // timing probe:
    // identical launch, identical output; T14 - T11 = one k_rec duration.
}

// Round 15
// 73.550 us; speedup vs baseline: 1.6156x; 1.6156x over previous
//
#include <hip/hip_runtime.h>
#include <hip/hip_bf16.h>

// Problem sizes (fixed by the reference)
#define S_LEN 256     // sequence length (t)
#define DM    512     // d_model (k / d)
#define DR    512     // d_rnn (s)

typedef float f4 __attribute__((ext_vector_type(4)));
typedef float f2 __attribute__((ext_vector_type(2)));

// ws layout (floats):
//   xT : [512][256]  at 0  (131072)

__global__ __launch_bounds__(256) void k_transpose_x(const float* __restrict__ x,
                                                     float* __restrict__ xT) {
    __shared__ float tile[32][33];
    const int k0 = blockIdx.x * 32;
    const int t0 = blockIdx.y * 32;
    const int lx = threadIdx.x & 31;
    const int ly = threadIdx.x >> 5;
#pragma unroll
    for (int i = 0; i < 32; i += 8)
        tile[ly + i][lx] = x[(t0 + ly + i) * DM + k0 + lx];
    __syncthreads();
#pragma unroll
    for (int i = 0; i < 32; i += 8)
        xT[(k0 + ly + i) * S_LEN + t0 + lx] = tile[lx][ly + i];
}

// grid(512) x 256: block = one s-row (XCD-banded). Phase 1: GEMM rows
// {s, 512+s} over all t (lane = t, coalesced xT loads, wave-uniform W1) +
// activation epilogue -> a,c straight into LDS (no global roundtrip).
// Phase 2: recurrence + y stream, f2 per thread, nt stores.
// 512 blocks = 2 blocks/CU = 8 waves/CU: double the TLP of the R11 split
// version for both the GEMM latency chain and the store stream.
__global__ __launch_bounds__(256) void k_fused(const float* __restrict__ x,
                                               const float* __restrict__ xT,
                                               const float* __restrict__ state0,
                                               const float* __restrict__ W1,
                                               const float* __restrict__ b1,
                                               const float* __restrict__ Lam,
                                               f2* __restrict__ out2) {
    const int bx  = blockIdx.x;                 // 0..511
    const int s   = (bx & 7) * 64 + (bx >> 3);  // bijective XCD s-banding
    const int tid = threadIdx.x;

    __shared__ f2 ac_l[S_LEN];                  // {a, c} per t (2 KB)

    // ---- Phase 1: GEMM + activations (lane = t) ----
    {
        const int t = tid;
        float acc_i = 0.f, acc_r = 0.f;
        const float* __restrict__ xb = xT + t;
        const float* __restrict__ wi = W1 + s * DM;          // wave-uniform
        const float* __restrict__ wr = W1 + (DR + s) * DM;   // wave-uniform

#pragma unroll 8
        for (int k = 0; k < DM; ++k) {
            const float xv = xb[k * S_LEN];
            acc_i = fmaf(xv, wi[k], acc_i);
            acc_r = fmaf(xv, wr[k], acc_r);
        }

        const float pre_i = acc_i + b1[s];
        const float pre_r = acc_r + b1[DR + s];
        const float inp = 1.f / (1.f + expf(-pre_i));    // sigmoid
        const float rec = 1.f / (1.f + expf(-pre_r));    // sigmoid
        const float sof = log1pf(expf(Lam[s]));          // softplus
        const float a   = expf(-8.f * sof * rec);
        const float c   = sqrtf(fmaxf(1.f - a * a, 0.f)) * inp;
        f2 ac; ac.x = a; ac.y = c;
        ac_l[t] = ac;
    }

    // ---- Phase 2: recurrence + y stream (thread = d-pair) ----
    const f2* __restrict__ st2 = reinterpret_cast<const f2*>(state0);
    const f2* __restrict__ x2  = reinterpret_cast<const f2*>(x);

    f2 h  = st2[s * 256 + tid];
    f2 xv = x2[tid];                     // t = 0 prefetch (independent of phase 1)

    __syncthreads();                     // ac_l ready

#pragma unroll 4
    for (int t = 0; t < S_LEN; ++t) {
        f2 xn;
        if (t + 1 < S_LEN) xn = x2[(t + 1) * 256 + tid];
        else xn = (f2)0.f;

        const f2 ac = ac_l[t];                     // wave-uniform LDS broadcast
        h.x = fmaf(ac.x, h.x, ac.y * xv.x);
        h.y = fmaf(ac.x, h.y, ac.y * xv.y);

        __builtin_nontemporal_store(h, &out2[(t * DR + s) * 256 + tid]);
        xv = xn;
    }
    // final state
    out2[(S_LEN * DR) * 256 + s * 256 + tid] = h;
}

extern "C" void kernel_launch(void* const* d_in, const int* in_sizes, int n_in,
                              void* d_out, int out_size, void* d_ws, size_t ws_size,
                              hipStream_t stream) {
    const float* x      = (const float*)d_in[0];
    const float* state0 = (const float*)d_in[1];
    const float* W1     = (const float*)d_in[2];
    const float* b1     = (const float*)d_in[3];
    const float* Lam    = (const float*)d_in[4];

    float* ws = (float*)d_ws;
    float* xT = ws;                       // 131072 floats

    f2* out2 = (f2*)d_out;

    k_transpose_x<<<dim3(16, 8), 256, 0, stream>>>(x, xT);
    k_fused<<<dim3(512), 256, 0, stream>>>(x, xT, state0, W1, b1, Lam, out2);
}

// Round 16
// 69.493 us; speedup vs baseline: 1.7099x; 1.0584x over previous
//
#include <hip/hip_runtime.h>
#include <hip/hip_bf16.h>

// Problem sizes (fixed by the reference)
#define S_LEN 256     // sequence length (t)
#define DM    512     // d_model (k / d)
#define DR    512     // d_rnn (s)

typedef float f4 __attribute__((ext_vector_type(4)));
typedef float f2 __attribute__((ext_vector_type(2)));

// Single fused kernel; no transpose, no workspace.
// grid(256) x 256: block = s-pair (XCD-banded).
// Phase 1 (lane = t): thread t reads x ROW t as 128 contiguous f4 loads and
//   reuses each f4 against all 4 W1 rows (i,r for both s) -> 16 FMA per load;
//   W1 rows are wave-uniform (s_load_dwordx4). This replaces the 1KB-stride
//   scalar xT walk whose interleaved vmcnt/lgkmcnt waits made the old GEMM
//   phase latency-bound (~25 us). Activations -> a,c into LDS.
// Phase 2: R11's k_rec loop verbatim (measured 44.4 us, ~6.1 TB/s y-stream).
__global__ __launch_bounds__(256) void k_fused(const float* __restrict__ x,
                                               const float* __restrict__ state0,
                                               const float* __restrict__ W1,
                                               const float* __restrict__ b1,
                                               const float* __restrict__ Lam,
                                               f4* __restrict__ out4) {
    const int bx  = blockIdx.x;                  // 0..255
    const int sp  = (bx & 7) * 32 + (bx >> 3);   // bijective XCD s-banding
    const int tid = threadIdx.x;
    const int s0  = sp * 2;
    const int s1  = sp * 2 + 1;

    __shared__ f2 ac_l[2][S_LEN];                // {a, c} per (half, t)

    // ---- Phase 1: GEMM + activations (lane = t = tid) ----
    {
        const f4* __restrict__ xr  = reinterpret_cast<const f4*>(x) + tid * (DM / 4);
        const f4* __restrict__ wi0 = reinterpret_cast<const f4*>(W1 + s0 * DM);
        const f4* __restrict__ wi1 = reinterpret_cast<const f4*>(W1 + s1 * DM);
        const f4* __restrict__ wr0 = reinterpret_cast<const f4*>(W1 + (DR + s0) * DM);
        const f4* __restrict__ wr1 = reinterpret_cast<const f4*>(W1 + (DR + s1) * DM);

        float ai0 = 0.f, ai1 = 0.f, ar0 = 0.f, ar1 = 0.f;

#pragma unroll 8
        for (int j = 0; j < DM / 4; ++j) {
            const f4 xv = xr[j];                 // contiguous per-thread stream
            const f4 a = wi0[j];                 // wave-uniform -> s_load_dwordx4
            const f4 b = wi1[j];
            const f4 c = wr0[j];
            const f4 d = wr1[j];
            ai0 = fmaf(xv.x, a.x, ai0); ai0 = fmaf(xv.y, a.y, ai0);
            ai0 = fmaf(xv.z, a.z, ai0); ai0 = fmaf(xv.w, a.w, ai0);
            ai1 = fmaf(xv.x, b.x, ai1); ai1 = fmaf(xv.y, b.y, ai1);
            ai1 = fmaf(xv.z, b.z, ai1); ai1 = fmaf(xv.w, b.w, ai1);
            ar0 = fmaf(xv.x, c.x, ar0); ar0 = fmaf(xv.y, c.y, ar0);
            ar0 = fmaf(xv.z, c.z, ar0); ar0 = fmaf(xv.w, c.w, ar0);
            ar1 = fmaf(xv.x, d.x, ar1); ar1 = fmaf(xv.y, d.y, ar1);
            ar1 = fmaf(xv.z, d.z, ar1); ar1 = fmaf(xv.w, d.w, ar1);
        }

#pragma unroll
        for (int j = 0; j < 2; ++j) {
            const float pre_i = (j ? ai1 : ai0) + b1[(j ? s1 : s0)];
            const float pre_r = (j ? ar1 : ar0) + b1[DR + (j ? s1 : s0)];
            const float inp = 1.f / (1.f + expf(-pre_i));    // sigmoid
            const float rec = 1.f / (1.f + expf(-pre_r));    // sigmoid
            const float sof = log1pf(expf(Lam[(j ? s1 : s0)])); // softplus
            const float a   = expf(-8.f * sof * rec);
            const float c   = sqrtf(fmaxf(1.f - a * a, 0.f)) * inp;
            f2 ac; ac.x = a; ac.y = c;
            ac_l[j][tid] = ac;
        }
    }

    // ---- Phase 2: recurrence + y stream (thread = (half, dq)) ----
    const int half = tid >> 7;           // 0 or 1
    const int s    = sp * 2 + half;
    const int dq   = tid & 127;          // d/4

    const f4* __restrict__ st4 = reinterpret_cast<const f4*>(state0);
    f4 h = st4[s * 128 + dq];

    const f4* __restrict__ x4 = reinterpret_cast<const f4*>(x);
    f4 xv = x4[dq];                      // t = 0 prefetch

    __syncthreads();                     // ac_l ready

#pragma unroll 4
    for (int t = 0; t < S_LEN; ++t) {
        f4 xn;
        if (t + 1 < S_LEN) xn = x4[(t + 1) * 128 + dq];
        else xn = (f4)0.f;

        const f2 ac = ac_l[half][t];               // wave-uniform LDS broadcast
        const float at = ac.x, ct = ac.y;
        h.x = fmaf(at, h.x, ct * xv.x);
        h.y = fmaf(at, h.y, ct * xv.y);
        h.z = fmaf(at, h.z, ct * xv.z);
        h.w = fmaf(at, h.w, ct * xv.w);

        __builtin_nontemporal_store(h, &out4[(t * DR + s) * 128 + dq]);
        xv = xn;
    }
    // final state
    out4[(S_LEN * DR) * 128 + s * 128 + dq] = h;
}

extern "C" void kernel_launch(void* const* d_in, const int* in_sizes, int n_in,
                              void* d_out, int out_size, void* d_ws, size_t ws_size,
                              hipStream_t stream) {
    const float* x      = (const float*)d_in[0];
    const float* state0 = (const float*)d_in[1];
    const float* W1     = (const float*)d_in[2];
    const float* b1     = (const float*)d_in[3];
    const float* Lam    = (const float*)d_in[4];

    f4* out4 = (f4*)d_out;

    k_fused<<<dim3(256), 256, 0, stream>>>(x, state0, W1, b1, Lam, out4);
}